// Round 3
// baseline (75.708 us; speedup 1.0000x reference)
//
#include <hip/hip_runtime.h>

// Problem constants (from reference setup_inputs)
#define B_  16
#define T_  4096
#define C_  512
#define K_  4
#define NT_ 64              // chunks along T
#define L_  (T_ / NT_)      // 64 steps per chunk
#define C4_ (C_ / 4)        // 128 float4 lanes per row

typedef float nfloat4 __attribute__((ext_vector_type(4)));  // native vec for nontemporal builtin

__device__ __forceinline__ float sigmoid_clamp(float la) {
    float av = 1.0f / (1.0f + expf(-la));
    return fminf(fmaxf(av, 1e-4f), 1.0f - 1e-4f);
}

// Pass 1: per (b, chunk j, c4) compute zero-init partial scans s_k(j), float4-wide.
// ws layout (scalar): ws[((b*K + k)*NT + j)*C + c]
__global__ __launch_bounds__(256) void ema_pass1(const float4* __restrict__ x4,
                                                 const float* __restrict__ logit_alpha,
                                                 float4* __restrict__ ws4) {
    const int c4 = threadIdx.x & (C4_ - 1);
    const int jh = threadIdx.x >> 7;                 // 0..1: two chunks per block
    const int b  = blockIdx.x / (NT_ / 2);
    const int j  = (blockIdx.x % (NT_ / 2)) * 2 + jh;

    float4 a[K_], oma[K_], s[K_];
#pragma unroll
    for (int k = 0; k < K_; ++k) {
        float4 la = ((const float4*)logit_alpha)[k * C4_ + c4];
        a[k].x = sigmoid_clamp(la.x); a[k].y = sigmoid_clamp(la.y);
        a[k].z = sigmoid_clamp(la.z); a[k].w = sigmoid_clamp(la.w);
        oma[k].x = 1.0f - a[k].x; oma[k].y = 1.0f - a[k].y;
        oma[k].z = 1.0f - a[k].z; oma[k].w = 1.0f - a[k].w;
        s[k].x = s[k].y = s[k].z = s[k].w = 0.0f;
    }

    const float4* xp = x4 + ((size_t)b * T_ + (size_t)j * L_) * C4_ + c4;
#pragma unroll 4
    for (int i = 0; i < L_; ++i) {
        float4 xv = xp[(size_t)i * C4_];
#pragma unroll
        for (int k = 0; k < K_; ++k) {
            s[k].x = fmaf(a[k].x, s[k].x, oma[k].x * xv.x);
            s[k].y = fmaf(a[k].y, s[k].y, oma[k].y * xv.y);
            s[k].z = fmaf(a[k].z, s[k].z, oma[k].z * xv.z);
            s[k].w = fmaf(a[k].w, s[k].w, oma[k].w * xv.w);
        }
    }

#pragma unroll
    for (int k = 0; k < K_; ++k)
        ws4[(((size_t)b * K_ + k) * NT_ + j) * C4_ + c4] = s[k];
}

// Pass 2: per (b, k, c) sequentially combine chunk summaries into carries.
// Grid split: 4 c-tiles of 128 so all 256 blocks -> 256 CUs participate.
// In-place: ws[j] := carry INTO chunk j; carry(0) = x[b,0,c].
__global__ __launch_bounds__(128) void ema_pass2(const float* __restrict__ x,
                                                 const float* __restrict__ logit_alpha,
                                                 float* __restrict__ ws) {
    const int ct = blockIdx.x & 3;                   // c tile 0..3
    const int bk = blockIdx.x >> 2;
    const int b  = bk / K_;
    const int k  = bk % K_;
    const int c  = ct * 128 + threadIdx.x;

    float av = sigmoid_clamp(logit_alpha[k * C_ + c]);
    float A = av;                                    // A = a^L, L=64=2^6
#pragma unroll
    for (int q = 0; q < 6; ++q) A *= A;

    float carry = x[(size_t)b * T_ * C_ + c];        // seed: y[-1] := x[b,0,c]
    float* wsb = ws + ((size_t)b * K_ + k) * NT_ * C_ + c;
    for (int j = 0; j < NT_; ++j) {
        float sj = wsb[(size_t)j * C_];
        wsb[(size_t)j * C_] = carry;
        carry = fmaf(A, carry, sj);
    }
}

// Pass 3: re-scan each chunk from its carry, mix with softmax weights,
// nontemporal float4 stores (out never re-read; keep x L3-resident).
__global__ __launch_bounds__(256) void ema_pass3(const float4* __restrict__ x4,
                                                 const float* __restrict__ logit_alpha,
                                                 const float4* __restrict__ ml4,
                                                 const float4* __restrict__ ws4,
                                                 float4* __restrict__ out4) {
    const int c4 = threadIdx.x & (C4_ - 1);
    const int jh = threadIdx.x >> 7;
    const int b  = blockIdx.x / (NT_ / 2);
    const int j  = (blockIdx.x % (NT_ / 2)) * 2 + jh;

    float4 a[K_], oma[K_], y[K_];
    float  m[K_][4];
#pragma unroll
    for (int k = 0; k < K_; ++k) {
        float4 la = ((const float4*)logit_alpha)[k * C4_ + c4];
        a[k].x = sigmoid_clamp(la.x); a[k].y = sigmoid_clamp(la.y);
        a[k].z = sigmoid_clamp(la.z); a[k].w = sigmoid_clamp(la.w);
        oma[k].x = 1.0f - a[k].x; oma[k].y = 1.0f - a[k].y;
        oma[k].z = 1.0f - a[k].z; oma[k].w = 1.0f - a[k].w;
        y[k] = ws4[(((size_t)b * K_ + k) * NT_ + j) * C4_ + c4];
    }

    // softmax over mix_logits[c][0..K): one float4 per channel (K=4 contiguous)
#pragma unroll
    for (int ci = 0; ci < 4; ++ci) {
        float4 ml = ml4[(size_t)c4 * 4 + ci];
        float mx = fmaxf(fmaxf(ml.x, ml.y), fmaxf(ml.z, ml.w));
        float e0 = expf(ml.x - mx), e1 = expf(ml.y - mx);
        float e2 = expf(ml.z - mx), e3 = expf(ml.w - mx);
        float inv = 1.0f / (e0 + e1 + e2 + e3);
        m[0][ci] = e0 * inv; m[1][ci] = e1 * inv;
        m[2][ci] = e2 * inv; m[3][ci] = e3 * inv;
    }

    const float4* xp = x4   + ((size_t)b * T_ + (size_t)j * L_) * C4_ + c4;
    float4*       op = out4 + ((size_t)b * T_ + (size_t)j * L_) * C4_ + c4;
#pragma unroll 4
    for (int i = 0; i < L_; ++i) {
        float4 xv = xp[(size_t)i * C4_];
        float4 acc; acc.x = acc.y = acc.z = acc.w = 0.0f;
#pragma unroll
        for (int k = 0; k < K_; ++k) {
            y[k].x = fmaf(a[k].x, y[k].x, oma[k].x * xv.x);
            y[k].y = fmaf(a[k].y, y[k].y, oma[k].y * xv.y);
            y[k].z = fmaf(a[k].z, y[k].z, oma[k].z * xv.z);
            y[k].w = fmaf(a[k].w, y[k].w, oma[k].w * xv.w);
            acc.x = fmaf(m[k][0], y[k].x, acc.x);
            acc.y = fmaf(m[k][1], y[k].y, acc.y);
            acc.z = fmaf(m[k][2], y[k].z, acc.z);
            acc.w = fmaf(m[k][3], y[k].w, acc.w);
        }
        nfloat4 nv = { acc.x, acc.y, acc.z, acc.w };
        __builtin_nontemporal_store(nv, (nfloat4*)&op[(size_t)i * C4_]);
    }
}

extern "C" void kernel_launch(void* const* d_in, const int* in_sizes, int n_in,
                              void* d_out, int out_size, void* d_ws, size_t ws_size,
                              hipStream_t stream) {
    const float* x           = (const float*)d_in[0];
    const float* logit_alpha = (const float*)d_in[1];
    const float* mix_logits  = (const float*)d_in[2];
    float* out = (float*)d_out;
    float* ws  = (float*)d_ws;   // needs B*K*NT*C*4 = 8 MiB

    ema_pass1<<<B_ * NT_ / 2, 256, 0, stream>>>((const float4*)x, logit_alpha,
                                                (float4*)ws);
    ema_pass2<<<B_ * K_ * 4, 128, 0, stream>>>(x, logit_alpha, ws);
    ema_pass3<<<B_ * NT_ / 2, 256, 0, stream>>>((const float4*)x, logit_alpha,
                                                (const float4*)mix_logits,
                                                (const float4*)ws, (float4*)out);
}